// Round 9
// baseline (1999.489 us; speedup 1.0000x reference)
//
#include <hip/hip_runtime.h>
#include <math.h>

#define NN 50000
#define NE 800000
#define NG 256
#define H 128
#define NIN 64
#define EIN 16
#define NL 3
#define LEPS 1e-5f

typedef short bf16x8 __attribute__((ext_vector_type(8)));
typedef float f32x4 __attribute__((ext_vector_type(4)));

__device__ __forceinline__ short bf16rne(float x) {
  unsigned u = __float_as_uint(x);
  unsigned r = u + 0x7fff + ((u >> 16) & 1);
  return (short)(r >> 16);
}

__device__ __forceinline__ float wsum(float v) {
#pragma unroll
  for (int m = 1; m < 64; m <<= 1) v += __shfl_xor(v, m, 64);
  return v;
}

__device__ __forceinline__ float lds_f32(const short* p) {
  short2 s = *(const short2*)p;
  return __uint_as_float((unsigned)(unsigned short)s.x |
                         ((unsigned)(unsigned short)s.y << 16));
}

// ---------------- sort-by-dst pipeline (once per launch) ----------------
__global__ __launch_bounds__(256) void k_count(const int* __restrict__ eidx,
                                               unsigned* __restrict__ cnt) {
  int t = blockIdx.x * 256 + threadIdx.x;
  if (t < NE) atomicAdd(&cnt[eidx[NE + t]], 1u);
}

__global__ __launch_bounds__(1024) void k_scan(const unsigned* __restrict__ cnt,
                                               unsigned* __restrict__ rowptr) {
  __shared__ unsigned part[16];
  __shared__ unsigned carry_s;
  const int tid = threadIdx.x, lane = tid & 63, wid = tid >> 6;
  if (tid == 0) carry_s = 0;
  __syncthreads();
  for (int base = 0; base < NN; base += 1024) {
    int i = base + tid;
    unsigned v = (i < NN) ? cnt[i] : 0u;
    unsigned incl = v;
#pragma unroll
    for (int off = 1; off < 64; off <<= 1) {
      unsigned t = __shfl_up(incl, off, 64);
      if (lane >= off) incl += t;
    }
    if (lane == 63) part[wid] = incl;
    __syncthreads();
    if (tid == 0) {
      unsigned s = 0;
#pragma unroll
      for (int w = 0; w < 16; w++) { unsigned t = part[w]; part[w] = s; s += t; }
    }
    __syncthreads();
    unsigned carry = carry_s;
    if (i < NN) rowptr[i] = carry + part[wid] + incl - v;
    __syncthreads();
    if (tid == 1023) carry_s = carry + part[15] + incl;
    __syncthreads();
  }
}

__global__ __launch_bounds__(256) void k_scatter(
    const int* __restrict__ eidx, const float* __restrict__ ea,
    const unsigned* __restrict__ rowptr, unsigned* __restrict__ cursor,
    int* __restrict__ src_s, int* __restrict__ dst_s,
    short* __restrict__ ea_bf) {
  int t = blockIdx.x * 256 + threadIdx.x;
  if (t >= NE) return;
  int s = eidx[t], d = eidx[NE + t];
  unsigned pos = rowptr[d] + atomicAdd(&cursor[d], 1u);
  src_s[pos] = s;
  dst_s[pos] = d;
  const float4* er = (const float4*)(ea + (size_t)t * EIN);
  float4 q0 = er[0], q1 = er[1], q2 = er[2], q3 = er[3];
  short tmp[16];
  tmp[0]=bf16rne(q0.x); tmp[1]=bf16rne(q0.y); tmp[2]=bf16rne(q0.z); tmp[3]=bf16rne(q0.w);
  tmp[4]=bf16rne(q1.x); tmp[5]=bf16rne(q1.y); tmp[6]=bf16rne(q1.z); tmp[7]=bf16rne(q1.w);
  tmp[8]=bf16rne(q2.x); tmp[9]=bf16rne(q2.y); tmp[10]=bf16rne(q2.z); tmp[11]=bf16rne(q2.w);
  tmp[12]=bf16rne(q3.x); tmp[13]=bf16rne(q3.y); tmp[14]=bf16rne(q3.z); tmp[15]=bf16rne(q3.w);
  short* dstp = ea_bf + (size_t)pos * EIN;
  *(bf16x8*)dstp = *(bf16x8*)tmp;
  *(bf16x8*)(dstp + 8) = *(bf16x8*)(tmp + 8);
}

// ---------------- K0: pre-swizzle all weights to bf16 B-fragment layout -------
__global__ __launch_bounds__(256) void k_convert_w(
    const float* __restrict__ gate_w, const float* __restrict__ msg_w1,
    const float* __restrict__ msg_w2, const float* __restrict__ e_enc_w,
    const float* __restrict__ res_w1, const float* __restrict__ res_w2,
    short* __restrict__ bgh, short* __restrict__ bm2, short* __restrict__ benc,
    short* __restrict__ brs1, short* __restrict__ brs2) {
  const int S_BGH = 3 * 65536;
  const int S_BM2 = S_BGH + 3 * 16384;
  const int S_BEN = S_BM2 + 4096;
  const int S_BR1 = S_BEN + 3 * 32768;
  const int S_BR2 = S_BR1 + 3 * 16384;
  int tid = blockIdx.x * 256 + threadIdx.x;
  if (tid >= S_BR2) return;
  if (tid < S_BGH) {
    int l = tid / 65536, e = tid % 65536;
    int f = e >> 9, lane = (e >> 3) & 63, j = e & 7;
    int nt = f >> 3, ks = f & 7;
    int k = ks * 32 + (lane >> 4) * 8 + j;
    int n = nt * 16 + (lane & 15);
    float v = (n < 128) ? gate_w[((size_t)l * 256 + k) * 128 + n]
                        : msg_w1[((size_t)l * 256 + k) * 128 + (n - 128)];
    bgh[tid] = bf16rne(v);
  } else if (tid < S_BM2) {
    int e0 = tid - S_BGH;
    int l = e0 / 16384, e = e0 % 16384;
    int f = e >> 9, lane = (e >> 3) & 63, j = e & 7;
    int nt = f >> 2, ks = f & 3;
    int k = ks * 32 + (lane >> 4) * 8 + j;
    int n = nt * 16 + (lane & 15);
    bm2[e0] = bf16rne(msg_w2[((size_t)l * 128 + k) * 128 + n]);
  } else if (tid < S_BEN) {
    int e = tid - S_BM2;
    int nt = e >> 9, lane = (e >> 3) & 63, j = e & 7;
    int k = (lane >> 4) * 8 + j;
    int n = nt * 16 + (lane & 15);
    benc[e] = (k < EIN) ? bf16rne(e_enc_w[k * H + n]) : (short)0;
  } else if (tid < S_BR1) {
    int e0 = tid - S_BEN;
    int l = e0 / 32768, e = e0 % 32768;
    int f = e >> 9, lane = (e >> 3) & 63, j = e & 7;
    int nt = f >> 3, ks = f & 7;
    int k = ks * 32 + (lane >> 4) * 8 + j;
    int n = nt * 16 + (lane & 15);
    brs1[e0] = bf16rne(res_w1[((size_t)l * 256 + k) * 128 + n]);
  } else {
    int e0 = tid - S_BR1;
    int l = e0 / 16384, e = e0 % 16384;
    int f = e >> 9, lane = (e >> 3) & 63, j = e & 7;
    int nt = f >> 2, ks = f & 3;
    int k = ks * 32 + (lane >> 4) * 8 + j;
    int n = nt * 16 + (lane & 15);
    brs2[e0] = bf16rne(res_w2[((size_t)l * 128 + k) * 128 + n]);
  }
}

// ---------------- K1: h = LN(x @ Wn + bn), also emit bf16 copy ----------------
__global__ __launch_bounds__(256) void k_node_encode(
    const float* __restrict__ x, const float* __restrict__ W,
    const float* __restrict__ bias,
    const float* __restrict__ lng, const float* __restrict__ lnb,
    float* __restrict__ h, short* __restrict__ h_bf) {
  __shared__ float xs[4][8 * NIN];
  const int wave = threadIdx.x >> 6, lane = threadIdx.x & 63;
  const int n0 = (blockIdx.x * 4 + wave) * 8;
  float* xt = xs[wave];
  for (int i = lane; i < 8 * NIN; i += 64) {
    int idx = n0 * NIN + i;
    xt[i] = (idx < NN * NIN) ? x[idx] : 0.f;
  }
  __syncthreads();
  const int c0 = lane, c1 = lane + 64;
  float a0[8], a1[8];
#pragma unroll
  for (int j = 0; j < 8; j++) { a0[j] = 0.f; a1[j] = 0.f; }
  for (int k = 0; k < NIN; k++) {
    float w0 = W[k * H + c0], w1 = W[k * H + c1];
#pragma unroll
    for (int j = 0; j < 8; j++) {
      float xv = xt[j * NIN + k];
      a0[j] = fmaf(xv, w0, a0[j]);
      a1[j] = fmaf(xv, w1, a1[j]);
    }
  }
  const float b0 = bias[c0], b1 = bias[c1];
  const float g0 = lng[c0], g1 = lng[c1], lb0 = lnb[c0], lb1 = lnb[c1];
#pragma unroll
  for (int j = 0; j < 8; j++) {
    float v0 = a0[j] + b0, v1 = a1[j] + b1;
    float mean = wsum(v0 + v1) * (1.f / H);
    float d0 = v0 - mean, d1 = v1 - mean;
    float var = wsum(d0 * d0 + d1 * d1) * (1.f / H);
    float rs = rsqrtf(var + LEPS);
    int n = n0 + j;
    if (n < NN) {
      float o0 = d0 * rs * g0 + lb0, o1 = d1 * rs * g1 + lb1;
      h[n * H + c0] = o0;
      h[n * H + c1] = o1;
      h_bf[n * H + c0] = bf16rne(o0);
      h_bf[n * H + c1] = bf16rne(o1);
    }
  }
}

// ---------------- K3: MFMA edge kernel, 32 edges/wave, dst-sorted -------------
// Two 16-row blocks per wave share every loaded B-fragment (2 MFMAs per load).
// Encoder runs BEFORE the h-gather fragment loads so vals[8][4] doesn't overlap
// af0/af1 (peak live-set ~164 regs). (256,3) -> 3 waves/SIMD; watch FETCH/WRITE
// for spill (R5/R6 signature: symmetric ~GB traffic).
__global__ __launch_bounds__(256, 3) void k_edge_mfma(
    const short* __restrict__ ea_bf, const int* __restrict__ src_s,
    const int* __restrict__ dst_s, const short* __restrict__ h_bf,
    const short* __restrict__ Benc, const float* __restrict__ be,
    const float* __restrict__ elng, const float* __restrict__ elnb,
    const short* __restrict__ Bgh, const short* __restrict__ Bm2,
    const float* __restrict__ gbias, const float* __restrict__ mbias1,
    const float* __restrict__ mbias2,
    float* __restrict__ agg) {
  __shared__ short regn[4][2][16 * 136];
  __shared__ int dsts[4][32];
  const int tid = threadIdx.x;
  const int wave = tid >> 6, lane = tid & 63;
  const int e0 = blockIdx.x * 128 + wave * 32;
  short* R0 = regn[wave][0];
  short* R1 = regn[wave][1];
  const int mrow = lane & 15, quad = lane >> 4;

  if (lane < 32) dsts[wave][lane] = dst_s[e0 + lane];

  // ---- encoder first (keeps vals[8][4] from overlapping af frags) ----
  {
    float gE[8], bE[8], beV[8];
#pragma unroll
    for (int nt = 0; nt < 8; nt++) {
      int col = nt * 16 + mrow;
      beV[nt] = be[col]; gE[nt] = elng[col]; bE[nt] = elnb[col];
    }
    for (int rb = 0; rb < 2; rb++) {
      short* R = rb ? R1 : R0;
      const int base = e0 + rb * 16;
      bf16x8 ae = (bf16x8){0, 0, 0, 0, 0, 0, 0, 0};
      if (quad < 2)
        ae = *(const bf16x8*)(ea_bf + (size_t)(base + mrow) * EIN + quad * 8);
      float vals[8][4];
#pragma unroll
      for (int nt = 0; nt < 8; nt++) {
        bf16x8 bf = *(const bf16x8*)(Benc + (nt * 64 + lane) * 8);
        f32x4 c = __builtin_amdgcn_mfma_f32_16x16x32_bf16(
            ae, bf, (f32x4){0.f, 0.f, 0.f, 0.f}, 0, 0, 0);
#pragma unroll
        for (int r = 0; r < 4; r++) vals[nt][r] = c[r] + beV[nt];
      }
#pragma unroll
      for (int r = 0; r < 4; r++) {
        float s1 = 0.f, s2 = 0.f;
#pragma unroll
        for (int nt = 0; nt < 8; nt++) {
          s1 += vals[nt][r];
          s2 = fmaf(vals[nt][r], vals[nt][r], s2);
        }
#pragma unroll
        for (int m = 1; m < 16; m <<= 1) {
          s1 += __shfl_xor(s1, m, 64);
          s2 += __shfl_xor(s2, m, 64);
        }
        float mean = s1 * (1.f / 128.f);
        float var = s2 * (1.f / 128.f) - mean * mean;
        float rs = rsqrtf(var + LEPS);
        int row = quad * 4 + r;
#pragma unroll
        for (int nt = 0; nt < 8; nt++)
          R[row * 136 + nt * 16 + mrow] =
              bf16rne((vals[nt][r] - mean) * rs * gE[nt] + bE[nt]);
      }
    }
  }

  // ---- now load A-frags: h part (global gather) + e part (LDS) ----
  const int srow0 = src_s[e0 + mrow];
  const int srow1 = src_s[e0 + 16 + mrow];
  bf16x8 af0[8], af1[8];
#pragma unroll
  for (int ks = 0; ks < 4; ks++) {
    af0[ks] = *(const bf16x8*)(h_bf + (size_t)srow0 * H + ks * 32 + quad * 8);
    af1[ks] = *(const bf16x8*)(h_bf + (size_t)srow1 * H + ks * 32 + quad * 8);
    af0[4 + ks] = *(const bf16x8*)&R0[mrow * 136 + ks * 32 + quad * 8];
    af1[4 + ks] = *(const bf16x8*)&R1[mrow * 136 + ks * 32 + quad * 8];
  }

  // ---- hidden pass: each B-frag feeds 2 MFMAs; relu -> T2 in R ----
#pragma unroll
  for (int t = 0; t < 8; t++) {
    f32x4 a0 = (f32x4){0.f, 0.f, 0.f, 0.f};
    f32x4 a1 = (f32x4){0.f, 0.f, 0.f, 0.f};
#pragma unroll
    for (int ks = 0; ks < 8; ks++) {
      bf16x8 bf = *(const bf16x8*)(Bgh + (size_t)(((t + 8) * 8 + ks) * 64 + lane) * 8);
      a0 = __builtin_amdgcn_mfma_f32_16x16x32_bf16(af0[ks], bf, a0, 0, 0, 0);
      a1 = __builtin_amdgcn_mfma_f32_16x16x32_bf16(af1[ks], bf, a1, 0, 0, 0);
    }
    int col = t * 16 + mrow;
    float mb = mbias1[col];
#pragma unroll
    for (int r = 0; r < 4; r++) {
      R0[(quad * 4 + r) * 136 + col] = bf16rne(fmaxf(a0[r] + mb, 0.f));
      R1[(quad * 4 + r) * 136 + col] = bf16rne(fmaxf(a1[r] + mb, 0.f));
    }
  }

  // GEMM2 A-frags from T2 (snapshot before msg staging clobbers T2)
  bf16x8 a20[4], a21[4];
#pragma unroll
  for (int ks = 0; ks < 4; ks++) {
    a20[ks] = *(const bf16x8*)&R0[mrow * 136 + ks * 32 + quad * 8];
    a21[ks] = *(const bf16x8*)&R1[mrow * 136 + ks * 32 + quad * 8];
  }

  // ---- two halves: gate + msg per tile -> stage fp32 msg in R -> flush ----
#pragma unroll
  for (int half = 0; half < 2; half++) {
#pragma unroll
    for (int t4 = 0; t4 < 4; t4++) {
      int t = half * 4 + t4;
      f32x4 g0 = (f32x4){0.f, 0.f, 0.f, 0.f};
      f32x4 g1 = (f32x4){0.f, 0.f, 0.f, 0.f};
#pragma unroll
      for (int ks = 0; ks < 8; ks++) {
        bf16x8 bf = *(const bf16x8*)(Bgh + (size_t)((t * 8 + ks) * 64 + lane) * 8);
        g0 = __builtin_amdgcn_mfma_f32_16x16x32_bf16(af0[ks], bf, g0, 0, 0, 0);
        g1 = __builtin_amdgcn_mfma_f32_16x16x32_bf16(af1[ks], bf, g1, 0, 0, 0);
      }
      f32x4 m0 = (f32x4){0.f, 0.f, 0.f, 0.f};
      f32x4 m1 = (f32x4){0.f, 0.f, 0.f, 0.f};
#pragma unroll
      for (int ks = 0; ks < 4; ks++) {
        bf16x8 bf = *(const bf16x8*)(Bm2 + (size_t)((t * 4 + ks) * 64 + lane) * 8);
        m0 = __builtin_amdgcn_mfma_f32_16x16x32_bf16(a20[ks], bf, m0, 0, 0, 0);
        m1 = __builtin_amdgcn_mfma_f32_16x16x32_bf16(a21[ks], bf, m1, 0, 0, 0);
      }
      int col = t * 16 + mrow;
      float gb = gbias[col], mb2 = mbias2[col];
      int soff = (t4 * 16 + mrow) * 2;
#pragma unroll
      for (int r = 0; r < 4; r++) {
        float gate0 = __builtin_amdgcn_rcpf(1.f + __expf(-(g0[r] + gb)));
        float gate1 = __builtin_amdgcn_rcpf(1.f + __expf(-(g1[r] + gb)));
        float msg0 = gate0 * (m0[r] + mb2);
        float msg1 = gate1 * (m1[r] + mb2);
        unsigned u0 = __float_as_uint(msg0);
        unsigned u1 = __float_as_uint(msg1);
        *(short2*)&R0[(quad * 4 + r) * 136 + soff] =
            make_short2((short)(u0 & 0xffff), (short)(u0 >> 16));
        *(short2*)&R1[(quad * 4 + r) * 136 + soff] =
            make_short2((short)(u1 & 0xffff), (short)(u1 >> 16));
      }
    }
    // flush: lane owns column (half*64 + lane); run-reduce 32 sorted rows
    const int colg = half * 64 + lane;
    int cur = dsts[wave][0];
    float run = lds_f32(&R0[lane * 2]);
#pragma unroll
    for (int row = 1; row < 32; row++) {
      int d = dsts[wave][row];
      const short* Rp = (row < 16) ? R0 : R1;
      float v = lds_f32(&Rp[(row & 15) * 136 + lane * 2]);
      if (d == cur) {
        run += v;
      } else {
        atomicAdd(&agg[(size_t)cur * H + colg], run);
        cur = d; run = v;
      }
    }
    atomicAdd(&agg[(size_t)cur * H + colg], run);
  }
}

// ---------------- K4: node update via MFMA: h = LN(h + MLP([h,agg])) ----------
// Also zeroes agg after reading it (saves the per-layer memset).
__global__ __launch_bounds__(256) void k_node_up2(
    float* agg, const short* __restrict__ h_bf_in,
    const float* __restrict__ h_in,
    const short* __restrict__ Brs1, const short* __restrict__ Brs2,
    const float* __restrict__ rb1, const float* __restrict__ rb2,
    const float* __restrict__ lng, const float* __restrict__ lnb,
    float* __restrict__ h, short* __restrict__ h_bf) {
  __shared__ short regn[4][16 * 136];
  const int tid = threadIdx.x;
  const int wave = tid >> 6, lane = tid & 63;
  const int n0 = blockIdx.x * 64 + wave * 16;
  short* R = regn[wave];
  const int mrow = lane & 15, quad = lane >> 4;

  int nr = n0 + mrow; if (nr >= NN) nr = NN - 1;
  bf16x8 af[8];
#pragma unroll
  for (int ks = 0; ks < 4; ks++)
    af[ks] = *(const bf16x8*)(h_bf_in + (size_t)nr * H + ks * 32 + quad * 8);
#pragma unroll
  for (int ks = 0; ks < 4; ks++) {
    float4 u = *(const float4*)(agg + (size_t)nr * H + ks * 32 + quad * 8);
    float4 w = *(const float4*)(agg + (size_t)nr * H + ks * 32 + quad * 8 + 4);
    short tmp[8];
    tmp[0]=bf16rne(u.x); tmp[1]=bf16rne(u.y); tmp[2]=bf16rne(u.z); tmp[3]=bf16rne(u.w);
    tmp[4]=bf16rne(w.x); tmp[5]=bf16rne(w.y); tmp[6]=bf16rne(w.z); tmp[7]=bf16rne(w.w);
    af[4 + ks] = *(bf16x8*)tmp;
  }
  // zero agg for next layer (plain stores; kernel boundary orders vs next edge)
  float4 z4 = make_float4(0.f, 0.f, 0.f, 0.f);
#pragma unroll
  for (int ks = 0; ks < 4; ks++) {
    *(float4*)(agg + (size_t)nr * H + ks * 32 + quad * 8) = z4;
    *(float4*)(agg + (size_t)nr * H + ks * 32 + quad * 8 + 4) = z4;
  }

  // hidden = relu([h|agg] @ W1 + rb1) -> T2 in R
#pragma unroll
  for (int t = 0; t < 8; t++) {
    f32x4 a = (f32x4){0.f, 0.f, 0.f, 0.f};
#pragma unroll
    for (int ks = 0; ks < 8; ks++) {
      bf16x8 bf = *(const bf16x8*)(Brs1 + (size_t)((t * 8 + ks) * 64 + lane) * 8);
      a = __builtin_amdgcn_mfma_f32_16x16x32_bf16(af[ks], bf, a, 0, 0, 0);
    }
    int col = t * 16 + mrow;
    float b = rb1[col];
#pragma unroll
    for (int r = 0; r < 4; r++)
      R[(quad * 4 + r) * 136 + col] = bf16rne(fmaxf(a[r] + b, 0.f));
  }
  bf16x8 a2[4];
#pragma unroll
  for (int ks = 0; ks < 4; ks++)
    a2[ks] = *(const bf16x8*)&R[mrow * 136 + ks * 32 + quad * 8];

  // out2 = T2 @ W2; vals = h + out2 + rb2
  float vals[8][4];
  float gl[8], bl[8];
#pragma unroll
  for (int t = 0; t < 8; t++) {
    f32x4 a = (f32x4){0.f, 0.f, 0.f, 0.f};
#pragma unroll
    for (int ks = 0; ks < 4; ks++) {
      bf16x8 bf = *(const bf16x8*)(Brs2 + (size_t)((t * 4 + ks) * 64 + lane) * 8);
      a = __builtin_amdgcn_mfma_f32_16x16x32_bf16(a2[ks], bf, a, 0, 0, 0);
    }
    int col = t * 16 + mrow;
    float b2 = rb2[col];
    gl[t] = lng[col]; bl[t] = lnb[col];
#pragma unroll
    for (int r = 0; r < 4; r++) {
      int rowi = n0 + quad * 4 + r;
      int rl = rowi < NN ? rowi : NN - 1;
      vals[t][r] = h_in[(size_t)rl * H + col] + a[r] + b2;
    }
  }
  // LN per row + store
#pragma unroll
  for (int r = 0; r < 4; r++) {
    float s1 = 0.f, s2 = 0.f;
#pragma unroll
    for (int t = 0; t < 8; t++) {
      s1 += vals[t][r];
      s2 = fmaf(vals[t][r], vals[t][r], s2);
    }
#pragma unroll
    for (int m = 1; m < 16; m <<= 1) {
      s1 += __shfl_xor(s1, m, 64);
      s2 += __shfl_xor(s2, m, 64);
    }
    float mean = s1 * (1.f / 128.f);
    float var = s2 * (1.f / 128.f) - mean * mean;
    float rs = rsqrtf(var + LEPS);
    int rowi = n0 + quad * 4 + r;
    if (rowi < NN) {
#pragma unroll
      for (int t = 0; t < 8; t++) {
        int col = t * 16 + mrow;
        float o = (vals[t][r] - mean) * rs * gl[t] + bl[t];
        h[(size_t)rowi * H + col] = o;
        h_bf[(size_t)rowi * H + col] = bf16rne(o);
      }
    }
  }
}

// ---------------- K5: pooling, run-reduce over sorted batch ----------------
__global__ __launch_bounds__(256) void k_pool(
    const float* __restrict__ h, const int* __restrict__ batch,
    float* __restrict__ gsum, float* __restrict__ gcnt) {
  const int tid = threadIdx.x;
  const int col = tid & 127, half = tid >> 7;
  int n0 = blockIdx.x * 32 + half * 16;
  if (n0 >= NN) return;
  int end = n0 + 16; if (end > NN) end = NN;
  int cur = batch[n0];
  float run = h[(size_t)n0 * H + col];
  float cnt = 1.f;
  for (int n = n0 + 1; n < end; n++) {
    int b = batch[n];
    float v = h[(size_t)n * H + col];
    if (b == cur) { run += v; cnt += 1.f; }
    else {
      atomicAdd(&gsum[(size_t)cur * H + col], run);
      if (col == 0) atomicAdd(&gcnt[cur], cnt);
      cur = b; run = v; cnt = 1.f;
    }
  }
  atomicAdd(&gsum[(size_t)cur * H + col], run);
  if (col == 0) atomicAdd(&gcnt[cur], cnt);
}

// ---------------- K6: readout MLP ----------------
__global__ __launch_bounds__(128) void k_readout(
    const float* __restrict__ gsum, const float* __restrict__ gcnt,
    const float* __restrict__ W1, const float* __restrict__ b1,
    const float* __restrict__ W2, const float* __restrict__ b2,
    float* __restrict__ out) {
  __shared__ float gs[H];
  __shared__ float o1[H];
  int b = blockIdx.x, c = threadIdx.x;
  float cnt = fmaxf(gcnt[b], 1.f);
  gs[c] = gsum[b * H + c] / cnt;
  __syncthreads();
  float acc = b1[c];
  for (int k = 0; k < H; k++) acc = fmaf(gs[k], W1[k * H + c], acc);
  o1[c] = fmaxf(acc, 0.f);
  __syncthreads();
  if (c < 2) {
    float acc2 = b2[c];
    for (int k = 0; k < H; k++) acc2 = fmaf(o1[k], W2[k * 2 + c], acc2);
    out[b * 2 + c] = acc2;
  }
}

extern "C" void kernel_launch(void* const* d_in, const int* in_sizes, int n_in,
                              void* d_out, int out_size, void* d_ws, size_t ws_size,
                              hipStream_t stream) {
  (void)in_sizes; (void)n_in; (void)out_size; (void)ws_size;
  const float* x       = (const float*)d_in[0];
  const float* ea      = (const float*)d_in[1];
  const int*   eidx    = (const int*)d_in[2];
  const int*   batch   = (const int*)d_in[3];
  const float* n_enc_w = (const float*)d_in[4];
  const float* n_enc_b = (const float*)d_in[5];
  const float* e_enc_w = (const float*)d_in[6];
  const float* e_enc_b = (const float*)d_in[7];
  const float* n_ln_g  = (const float*)d_in[8];
  const float* n_ln_b  = (const float*)d_in[9];
  const float* e_ln_g  = (const float*)d_in[10];
  const float* e_ln_b  = (const float*)d_in[11];
  const float* msg_w1  = (const float*)d_in[12];
  const float* msg_b1  = (const float*)d_in[13];
  const float* msg_w2  = (const float*)d_in[14];
  const float* msg_b2  = (const float*)d_in[15];
  const float* gate_w  = (const float*)d_in[16];
  const float* gate_b  = (const float*)d_in[17];
  const float* res_w1  = (const float*)d_in[18];
  const float* res_b1  = (const float*)d_in[19];
  const float* res_w2  = (const float*)d_in[20];
  const float* res_b2  = (const float*)d_in[21];
  const float* ln_g    = (const float*)d_in[22];
  const float* ln_b    = (const float*)d_in[23];
  const float* ro_w1   = (const float*)d_in[24];
  const float* ro_b1   = (const float*)d_in[25];
  const float* ro_w2   = (const float*)d_in[26];
  const float* ro_b2   = (const float*)d_in[27];

  char* p = (char*)d_ws;
  float* h     = (float*)p;  p += (size_t)NN * H * 4;          // 25.6 MB
  short* h_bf  = (short*)p;  p += (size_t)NN * H * 2;          // 12.8 MB
  float* agg   = (float*)p;  p += (size_t)NN * H * 4;          // 25.6 MB
  short* ea_bf = (short*)p;  p += (size_t)NE * EIN * 2;        // 25.6 MB
  float* gsum  = (float*)p;  p += (size_t)NG * H * 4;
  float* gcnt  = (float*)p;  p += 1024;
  short* bgh   = (short*)p;  p += (size_t)3 * 65536 * 2;
  short* bm2   = (short*)p;  p += (size_t)3 * 16384 * 2;
  short* benc  = (short*)p;  p += (size_t)4096 * 2;
  short* brs1  = (short*)p;  p += (size_t)3 * 32768 * 2;
  short* brs2  = (short*)p;  p += (size_t)3 * 16384 * 2;
  unsigned* rowptr = (unsigned*)p; p += ((size_t)NN * 4 + 15) / 16 * 16;
  unsigned* cursor = (unsigned*)p; p += ((size_t)NN * 4 + 15) / 16 * 16;
  int* src_s   = (int*)p;    p += (size_t)NE * 4;
  int* dst_s   = (int*)p;    p += (size_t)NE * 4;
  // total ~97 MB

  const int node_blocks = (NN + 31) / 32;
  const int nup_blocks  = (NN + 63) / 64;   // 782
  const int edge_blocks = NE / 128;         // 6250, exact
  const int e256 = (NE + 255) / 256;

  hipMemsetAsync(cursor, 0, (size_t)NN * 4, stream);
  k_count<<<e256, 256, 0, stream>>>(eidx, cursor);
  k_scan<<<1, 1024, 0, stream>>>(cursor, rowptr);
  hipMemsetAsync(cursor, 0, (size_t)NN * 4, stream);
  k_scatter<<<e256, 256, 0, stream>>>(eidx, ea, rowptr, cursor, src_s, dst_s, ea_bf);

  k_convert_w<<<(3 * 81920 + 4096 + 3 * 49152 + 255) / 256, 256, 0, stream>>>(
      gate_w, msg_w1, msg_w2, e_enc_w, res_w1, res_w2,
      bgh, bm2, benc, brs1, brs2);
  k_node_encode<<<node_blocks, 256, 0, stream>>>(x, n_enc_w, n_enc_b, n_ln_g, n_ln_b, h, h_bf);

  // agg zeroed once here; k_node_up2 re-zeroes it for the next layer
  hipMemsetAsync(agg, 0, (size_t)NN * H * 4, stream);
  for (int l = 0; l < NL; l++) {
    k_edge_mfma<<<edge_blocks, 256, 0, stream>>>(
        ea_bf, src_s, dst_s, h_bf, benc, e_enc_b, e_ln_g, e_ln_b,
        bgh + (size_t)l * 65536, bm2 + (size_t)l * 16384,
        gate_b + l * H, msg_b1 + l * H, msg_b2 + l * H, agg);
    k_node_up2<<<nup_blocks, 256, 0, stream>>>(
        agg, h_bf, h,
        brs1 + (size_t)l * 32768, brs2 + (size_t)l * 16384,
        res_b1 + l * H, res_b2 + l * H,
        ln_g + l * H, ln_b + l * H, h, h_bf);
  }

  hipMemsetAsync(gsum, 0, ((size_t)NG * H + NG) * 4, stream);
  k_pool<<<(NN + 31) / 32, 256, 0, stream>>>(h, batch, gsum, gcnt);
  k_readout<<<NG, 128, 0, stream>>>(gsum, gcnt, ro_w1, ro_b1, ro_w2, ro_b2, (float*)d_out);
}

// Round 10
// 1161.313 us; speedup vs baseline: 1.7217x; 1.7217x over previous
//
#include <hip/hip_runtime.h>
#include <math.h>

#define NN 50000
#define NE 800000
#define NG 256
#define H 128
#define NIN 64
#define EIN 16
#define NL 3
#define LEPS 1e-5f

typedef short bf16x8 __attribute__((ext_vector_type(8)));
typedef float f32x4 __attribute__((ext_vector_type(4)));
typedef float f32x16 __attribute__((ext_vector_type(16)));

__device__ __forceinline__ short bf16rne(float x) {
  unsigned u = __float_as_uint(x);
  unsigned r = u + 0x7fff + ((u >> 16) & 1);
  return (short)(r >> 16);
}

__device__ __forceinline__ float wsum(float v) {
#pragma unroll
  for (int m = 1; m < 64; m <<= 1) v += __shfl_xor(v, m, 64);
  return v;
}

__device__ __forceinline__ float lds_f32(const short* p) {
  short2 s = *(const short2*)p;
  return __uint_as_float((unsigned)(unsigned short)s.x |
                         ((unsigned)(unsigned short)s.y << 16));
}

// ---------------- sort-by-dst pipeline (once per launch) ----------------
__global__ __launch_bounds__(256) void k_count(const int* __restrict__ eidx,
                                               unsigned* __restrict__ cnt) {
  int t = blockIdx.x * 256 + threadIdx.x;
  if (t < NE) atomicAdd(&cnt[eidx[NE + t]], 1u);
}

__global__ __launch_bounds__(1024) void k_scan(const unsigned* __restrict__ cnt,
                                               unsigned* __restrict__ rowptr) {
  __shared__ unsigned part[16];
  __shared__ unsigned carry_s;
  const int tid = threadIdx.x, lane = tid & 63, wid = tid >> 6;
  if (tid == 0) carry_s = 0;
  __syncthreads();
  for (int base = 0; base < NN; base += 1024) {
    int i = base + tid;
    unsigned v = (i < NN) ? cnt[i] : 0u;
    unsigned incl = v;
#pragma unroll
    for (int off = 1; off < 64; off <<= 1) {
      unsigned t = __shfl_up(incl, off, 64);
      if (lane >= off) incl += t;
    }
    if (lane == 63) part[wid] = incl;
    __syncthreads();
    if (tid == 0) {
      unsigned s = 0;
#pragma unroll
      for (int w = 0; w < 16; w++) { unsigned t = part[w]; part[w] = s; s += t; }
    }
    __syncthreads();
    unsigned carry = carry_s;
    if (i < NN) rowptr[i] = carry + part[wid] + incl - v;
    __syncthreads();
    if (tid == 1023) carry_s = carry + part[15] + incl;
    __syncthreads();
  }
}

__global__ __launch_bounds__(256) void k_scatter(
    const int* __restrict__ eidx, const float* __restrict__ ea,
    const unsigned* __restrict__ rowptr, unsigned* __restrict__ cursor,
    int* __restrict__ src_s, int* __restrict__ dst_s,
    short* __restrict__ ea_bf) {
  int t = blockIdx.x * 256 + threadIdx.x;
  if (t >= NE) return;
  int s = eidx[t], d = eidx[NE + t];
  unsigned pos = rowptr[d] + atomicAdd(&cursor[d], 1u);
  src_s[pos] = s;
  dst_s[pos] = d;
  const float4* er = (const float4*)(ea + (size_t)t * EIN);
  float4 q0 = er[0], q1 = er[1], q2 = er[2], q3 = er[3];
  short tmp[16];
  tmp[0]=bf16rne(q0.x); tmp[1]=bf16rne(q0.y); tmp[2]=bf16rne(q0.z); tmp[3]=bf16rne(q0.w);
  tmp[4]=bf16rne(q1.x); tmp[5]=bf16rne(q1.y); tmp[6]=bf16rne(q1.z); tmp[7]=bf16rne(q1.w);
  tmp[8]=bf16rne(q2.x); tmp[9]=bf16rne(q2.y); tmp[10]=bf16rne(q2.z); tmp[11]=bf16rne(q2.w);
  tmp[12]=bf16rne(q3.x); tmp[13]=bf16rne(q3.y); tmp[14]=bf16rne(q3.z); tmp[15]=bf16rne(q3.w);
  short* dstp = ea_bf + (size_t)pos * EIN;
  *(bf16x8*)dstp = *(bf16x8*)tmp;
  *(bf16x8*)(dstp + 8) = *(bf16x8*)(tmp + 8);
}

// ---------------- K0: pre-swizzle weights -----------------------------------
// Edge-kernel weights now in 32x32x16 B-frag layout:
//   elem ((f*64+lane)*8+j) <- W[k][n], k = ks*16 + (lane>>5)*8 + j,
//   n = nt*32 + (lane&31).  Bgh2: f = nt*16+ks (nt<8, over [gate|msg_w1]);
//   Bm22: f = nt*8+ks (nt<4); Benc2: f = t (K=16 exact, no padding).
// Node-update weights keep the 16x16x32 layout (brs1/brs2).
__global__ __launch_bounds__(256) void k_convert_w(
    const float* __restrict__ gate_w, const float* __restrict__ msg_w1,
    const float* __restrict__ msg_w2, const float* __restrict__ e_enc_w,
    const float* __restrict__ res_w1, const float* __restrict__ res_w2,
    short* __restrict__ bgh, short* __restrict__ bm2, short* __restrict__ benc,
    short* __restrict__ brs1, short* __restrict__ brs2) {
  const int S_BGH = 3 * 65536;
  const int S_BM2 = S_BGH + 3 * 16384;
  const int S_BEN = S_BM2 + 2048;
  const int S_BR1 = S_BEN + 3 * 32768;
  const int S_BR2 = S_BR1 + 3 * 16384;
  int tid = blockIdx.x * 256 + threadIdx.x;
  if (tid >= S_BR2) return;
  if (tid < S_BGH) {
    int l = tid / 65536, e = tid % 65536;
    int f = e >> 9, lane = (e >> 3) & 63, j = e & 7;
    int nt = f >> 4, ks = f & 15;
    int k = ks * 16 + (lane >> 5) * 8 + j;
    int n = nt * 32 + (lane & 31);
    float v = (n < 128) ? gate_w[((size_t)l * 256 + k) * 128 + n]
                        : msg_w1[((size_t)l * 256 + k) * 128 + (n - 128)];
    bgh[tid] = bf16rne(v);
  } else if (tid < S_BM2) {
    int e0 = tid - S_BGH;
    int l = e0 / 16384, e = e0 % 16384;
    int f = e >> 9, lane = (e >> 3) & 63, j = e & 7;
    int nt = f >> 3, ks = f & 7;
    int k = ks * 16 + (lane >> 5) * 8 + j;
    int n = nt * 32 + (lane & 31);
    bm2[e0] = bf16rne(msg_w2[((size_t)l * 128 + k) * 128 + n]);
  } else if (tid < S_BEN) {
    int e = tid - S_BM2;
    int t = e >> 9, lane = (e >> 3) & 63, j = e & 7;
    int k = (lane >> 5) * 8 + j;                 // < 16 always
    int n = t * 32 + (lane & 31);
    benc[e] = bf16rne(e_enc_w[k * H + n]);
  } else if (tid < S_BR1) {
    int e0 = tid - S_BEN;
    int l = e0 / 32768, e = e0 % 32768;
    int f = e >> 9, lane = (e >> 3) & 63, j = e & 7;
    int nt = f >> 3, ks = f & 7;
    int k = ks * 32 + (lane >> 4) * 8 + j;
    int n = nt * 16 + (lane & 15);
    brs1[e0] = bf16rne(res_w1[((size_t)l * 256 + k) * 128 + n]);
  } else {
    int e0 = tid - S_BR1;
    int l = e0 / 16384, e = e0 % 16384;
    int f = e >> 9, lane = (e >> 3) & 63, j = e & 7;
    int nt = f >> 2, ks = f & 3;
    int k = ks * 32 + (lane >> 4) * 8 + j;
    int n = nt * 16 + (lane & 15);
    brs2[e0] = bf16rne(res_w2[((size_t)l * 128 + k) * 128 + n]);
  }
}

// ---------------- K1: h = LN(x @ Wn + bn), also emit bf16 copy ----------------
__global__ __launch_bounds__(256) void k_node_encode(
    const float* __restrict__ x, const float* __restrict__ W,
    const float* __restrict__ bias,
    const float* __restrict__ lng, const float* __restrict__ lnb,
    float* __restrict__ h, short* __restrict__ h_bf) {
  __shared__ float xs[4][8 * NIN];
  const int wave = threadIdx.x >> 6, lane = threadIdx.x & 63;
  const int n0 = (blockIdx.x * 4 + wave) * 8;
  float* xt = xs[wave];
  for (int i = lane; i < 8 * NIN; i += 64) {
    int idx = n0 * NIN + i;
    xt[i] = (idx < NN * NIN) ? x[idx] : 0.f;
  }
  __syncthreads();
  const int c0 = lane, c1 = lane + 64;
  float a0[8], a1[8];
#pragma unroll
  for (int j = 0; j < 8; j++) { a0[j] = 0.f; a1[j] = 0.f; }
  for (int k = 0; k < NIN; k++) {
    float w0 = W[k * H + c0], w1 = W[k * H + c1];
#pragma unroll
    for (int j = 0; j < 8; j++) {
      float xv = xt[j * NIN + k];
      a0[j] = fmaf(xv, w0, a0[j]);
      a1[j] = fmaf(xv, w1, a1[j]);
    }
  }
  const float b0 = bias[c0], b1 = bias[c1];
  const float g0 = lng[c0], g1 = lng[c1], lb0 = lnb[c0], lb1 = lnb[c1];
#pragma unroll
  for (int j = 0; j < 8; j++) {
    float v0 = a0[j] + b0, v1 = a1[j] + b1;
    float mean = wsum(v0 + v1) * (1.f / H);
    float d0 = v0 - mean, d1 = v1 - mean;
    float var = wsum(d0 * d0 + d1 * d1) * (1.f / H);
    float rs = rsqrtf(var + LEPS);
    int n = n0 + j;
    if (n < NN) {
      float o0 = d0 * rs * g0 + lb0, o1 = d1 * rs * g1 + lb1;
      h[n * H + c0] = o0;
      h[n * H + c1] = o1;
      h_bf[n * H + c0] = bf16rne(o0);
      h_bf[n * H + c1] = bf16rne(o1);
    }
  }
}

// ---------------- K3: MFMA edge kernel, 32x32x16 shape, dst-sorted ------------
// One wave = one M=32 A-tile (32 edges). B-frag bytes per MAC halved vs
// 16x16x32 (R8 was L2-BW-bound at ~29 TB/s on 8.5 GB of B re-reads).
// Wave-private LDS region R [32][136] shorts holds, in turn:
// e (bf16) -> T2 hidden (bf16) -> msg half-tile (fp32 bits in short2).
// C/D layout: col=lane&31, row=(reg&3)+8*(reg>>2)+4*(lane>>5).
// A/B layout: m/n=lane&31, k=(lane>>5)*8+j.  NO launch-bounds clamp (R5/R6/R9).
__global__ __launch_bounds__(256) void k_edge_mfma(
    const short* __restrict__ ea_bf, const int* __restrict__ src_s,
    const int* __restrict__ dst_s, const short* __restrict__ h_bf,
    const short* __restrict__ Benc, const float* __restrict__ be,
    const float* __restrict__ elng, const float* __restrict__ elnb,
    const short* __restrict__ Bgh, const short* __restrict__ Bm2,
    const float* __restrict__ gbias, const float* __restrict__ mbias1,
    const float* __restrict__ mbias2,
    float* __restrict__ agg) {
  __shared__ short regn[4][32 * 136];   // 8.7 KB per wave, 34.8 KB per block
  __shared__ int dsts[4][32];
  const int tid = threadIdx.x;
  const int wave = tid >> 6, lane = tid & 63;
  const int e0 = blockIdx.x * 128 + wave * 32;
  short* R = regn[wave];
  const int c31 = lane & 31, halfl = lane >> 5;
  const int koff = halfl * 8;

  if (lane < 32) dsts[wave][lane] = dst_s[e0 + lane];

  // ---- encoder: e = LN(ea @ We + be), K=16 native ----
  {
    float gE[4], bE[4], beV[4];
#pragma unroll
    for (int t = 0; t < 4; t++) {
      int col = t * 32 + c31;
      beV[t] = be[col]; gE[t] = elng[col]; bE[t] = elnb[col];
    }
    bf16x8 ae = *(const bf16x8*)(ea_bf + (size_t)(e0 + c31) * EIN + koff);
    float vals[4][16];
#pragma unroll
    for (int t = 0; t < 4; t++) {
      bf16x8 bf = *(const bf16x8*)(Benc + (t * 64 + lane) * 8);
      f32x16 c = __builtin_amdgcn_mfma_f32_32x32x16_bf16(
          ae, bf, (f32x16)(0.f), 0, 0, 0);
#pragma unroll
      for (int r = 0; r < 16; r++) vals[t][r] = c[r] + beV[t];
    }
#pragma unroll
    for (int r = 0; r < 16; r++) {
      float s1 = vals[0][r] + vals[1][r] + vals[2][r] + vals[3][r];
      float s2 = fmaf(vals[0][r], vals[0][r],
                 fmaf(vals[1][r], vals[1][r],
                 fmaf(vals[2][r], vals[2][r], vals[3][r] * vals[3][r])));
#pragma unroll
      for (int m = 1; m < 32; m <<= 1) {
        s1 += __shfl_xor(s1, m, 64);
        s2 += __shfl_xor(s2, m, 64);
      }
      float mean = s1 * (1.f / 128.f);
      float var = s2 * (1.f / 128.f) - mean * mean;
      float rs = rsqrtf(var + LEPS);
      int row = (r & 3) + 8 * (r >> 2) + 4 * halfl;
#pragma unroll
      for (int t = 0; t < 4; t++)
        R[row * 136 + t * 32 + c31] =
            bf16rne((vals[t][r] - mean) * rs * gE[t] + bE[t]);
    }
  }

  // ---- A-frags: h part (global gather, k 0-127) + e part (LDS, k 128-255) ----
  const int srow = src_s[e0 + c31];
  bf16x8 af[16];
#pragma unroll
  for (int ks = 0; ks < 8; ks++)
    af[ks] = *(const bf16x8*)(h_bf + (size_t)srow * H + ks * 16 + koff);
#pragma unroll
  for (int ks = 0; ks < 8; ks++)
    af[8 + ks] = *(const bf16x8*)&R[c31 * 136 + ks * 16 + koff];

  // ---- hidden tiles (Bgh nt 4..7): relu -> T2 (overlays e in R) ----
#pragma unroll
  for (int ht = 0; ht < 4; ht++) {
    f32x16 a = (f32x16)(0.f);
#pragma unroll
    for (int ks = 0; ks < 16; ks++) {
      bf16x8 bf = *(const bf16x8*)(Bgh + (size_t)(((4 + ht) * 16 + ks) * 64 + lane) * 8);
      a = __builtin_amdgcn_mfma_f32_32x32x16_bf16(af[ks], bf, a, 0, 0, 0);
    }
    int col = ht * 32 + c31;
    float mb = mbias1[col];
#pragma unroll
    for (int r = 0; r < 16; r++) {
      int row = (r & 3) + 8 * (r >> 2) + 4 * halfl;
      R[row * 136 + col] = bf16rne(fmaxf(a[r] + mb, 0.f));
    }
  }

  // ---- gate tiles (Bgh nt 0..3): sigmoid -> regs ----
  float gate[4][16];
#pragma unroll
  for (int gt = 0; gt < 4; gt++) {
    f32x16 a = (f32x16)(0.f);
#pragma unroll
    for (int ks = 0; ks < 16; ks++) {
      bf16x8 bf = *(const bf16x8*)(Bgh + (size_t)((gt * 16 + ks) * 64 + lane) * 8);
      a = __builtin_amdgcn_mfma_f32_32x32x16_bf16(af[ks], bf, a, 0, 0, 0);
    }
    float gb = gbias[gt * 32 + c31];
#pragma unroll
    for (int r = 0; r < 16; r++)
      gate[gt][r] = __builtin_amdgcn_rcpf(1.f + __expf(-(a[r] + gb)));
  }

  // ---- GEMM2 A-frags from T2 (snapshot before msg staging clobbers) ----
  bf16x8 a2[8];
#pragma unroll
  for (int ks = 0; ks < 8; ks++)
    a2[ks] = *(const bf16x8*)&R[c31 * 136 + ks * 16 + koff];

  // ---- two halves: msg per tile -> stage fp32 in R -> flush ----
#pragma unroll
  for (int halfM = 0; halfM < 2; halfM++) {
#pragma unroll
    for (int t2 = 0; t2 < 2; t2++) {
      int gt = halfM * 2 + t2;
      f32x16 m = (f32x16)(0.f);
#pragma unroll
      for (int ks = 0; ks < 8; ks++) {
        bf16x8 bf = *(const bf16x8*)(Bm2 + (size_t)((gt * 8 + ks) * 64 + lane) * 8);
        m = __builtin_amdgcn_mfma_f32_32x32x16_bf16(a2[ks], bf, m, 0, 0, 0);
      }
      float mb2 = mbias2[gt * 32 + c31];
      int c2 = t2 * 32 + c31;
#pragma unroll
      for (int r = 0; r < 16; r++) {
        int row = (r & 3) + 8 * (r >> 2) + 4 * halfl;
        float msg = gate[gt][r] * (m[r] + mb2);
        unsigned u = __float_as_uint(msg);
        *(short2*)&R[row * 136 + c2 * 2] =
            make_short2((short)(u & 0xffff), (short)(u >> 16));
      }
    }
    // flush: lane owns column (halfM*64 + lane); run-reduce 32 sorted rows
    const int colg = halfM * 64 + lane;
    int cur = dsts[wave][0];
    float run = lds_f32(&R[lane * 2]);
#pragma unroll
    for (int row = 1; row < 32; row++) {
      int d = dsts[wave][row];
      float v = lds_f32(&R[row * 136 + lane * 2]);
      if (d == cur) {
        run += v;
      } else {
        atomicAdd(&agg[(size_t)cur * H + colg], run);
        cur = d; run = v;
      }
    }
    atomicAdd(&agg[(size_t)cur * H + colg], run);
  }
}

// ---------------- K4: node update via MFMA (16x16x32, unchanged from R8) ------
__global__ __launch_bounds__(256) void k_node_up2(
    float* agg, const short* __restrict__ h_bf_in,
    const float* __restrict__ h_in,
    const short* __restrict__ Brs1, const short* __restrict__ Brs2,
    const float* __restrict__ rb1, const float* __restrict__ rb2,
    const float* __restrict__ lng, const float* __restrict__ lnb,
    float* __restrict__ h, short* __restrict__ h_bf) {
  __shared__ short regn[4][16 * 136];
  const int tid = threadIdx.x;
  const int wave = tid >> 6, lane = tid & 63;
  const int n0 = blockIdx.x * 64 + wave * 16;
  short* R = regn[wave];
  const int mrow = lane & 15, quad = lane >> 4;

  int nr = n0 + mrow; if (nr >= NN) nr = NN - 1;
  bf16x8 af[8];
#pragma unroll
  for (int ks = 0; ks < 4; ks++)
    af[ks] = *(const bf16x8*)(h_bf_in + (size_t)nr * H + ks * 32 + quad * 8);
#pragma unroll
  for (int ks = 0; ks < 4; ks++) {
    float4 u = *(const float4*)(agg + (size_t)nr * H + ks * 32 + quad * 8);
    float4 w = *(const float4*)(agg + (size_t)nr * H + ks * 32 + quad * 8 + 4);
    short tmp[8];
    tmp[0]=bf16rne(u.x); tmp[1]=bf16rne(u.y); tmp[2]=bf16rne(u.z); tmp[3]=bf16rne(u.w);
    tmp[4]=bf16rne(w.x); tmp[5]=bf16rne(w.y); tmp[6]=bf16rne(w.z); tmp[7]=bf16rne(w.w);
    af[4 + ks] = *(bf16x8*)tmp;
  }
  float4 z4 = make_float4(0.f, 0.f, 0.f, 0.f);
#pragma unroll
  for (int ks = 0; ks < 4; ks++) {
    *(float4*)(agg + (size_t)nr * H + ks * 32 + quad * 8) = z4;
    *(float4*)(agg + (size_t)nr * H + ks * 32 + quad * 8 + 4) = z4;
  }

#pragma unroll
  for (int t = 0; t < 8; t++) {
    f32x4 a = (f32x4){0.f, 0.f, 0.f, 0.f};
#pragma unroll
    for (int ks = 0; ks < 8; ks++) {
      bf16x8 bf = *(const bf16x8*)(Brs1 + (size_t)((t * 8 + ks) * 64 + lane) * 8);
      a = __builtin_amdgcn_mfma_f32_16x16x32_bf16(af[ks], bf, a, 0, 0, 0);
    }
    int col = t * 16 + mrow;
    float b = rb1[col];
#pragma unroll
    for (int r = 0; r < 4; r++)
      R[(quad * 4 + r) * 136 + col] = bf16rne(fmaxf(a[r] + b, 0.f));
  }
  bf16x8 a2[4];
#pragma unroll
  for (int ks = 0; ks < 4; ks++)
    a2[ks] = *(const bf16x8*)&R[mrow * 136 + ks * 32 + quad * 8];

  float vals[8][4];
  float gl[8], bl[8];
#pragma unroll
  for (int t = 0; t < 8; t++) {
    f32x4 a = (f32x4){0.f, 0.f, 0.f, 0.f};
#pragma unroll
    for (int ks = 0; ks < 4; ks++) {
      bf16x8 bf = *(const bf16x8*)(Brs2 + (size_t)((t * 4 + ks) * 64 + lane) * 8);
      a = __builtin_amdgcn_mfma_f32_16x16x32_bf16(a2[ks], bf, a, 0, 0, 0);
    }
    int col = t * 16 + mrow;
    float b2 = rb2[col];
    gl[t] = lng[col]; bl[t] = lnb[col];
#pragma unroll
    for (int r = 0; r < 4; r++) {
      int rowi = n0 + quad * 4 + r;
      int rl = rowi < NN ? rowi : NN - 1;
      vals[t][r] = h_in[(size_t)rl * H + col] + a[r] + b2;
    }
  }
#pragma unroll
  for (int r = 0; r < 4; r++) {
    float s1 = 0.f, s2 = 0.f;
#pragma unroll
    for (int t = 0; t < 8; t++) {
      s1 += vals[t][r];
      s2 = fmaf(vals[t][r], vals[t][r], s2);
    }
#pragma unroll
    for (int m = 1; m < 16; m <<= 1) {
      s1 += __shfl_xor(s1, m, 64);
      s2 += __shfl_xor(s2, m, 64);
    }
    float mean = s1 * (1.f / 128.f);
    float var = s2 * (1.f / 128.f) - mean * mean;
    float rs = rsqrtf(var + LEPS);
    int rowi = n0 + quad * 4 + r;
    if (rowi < NN) {
#pragma unroll
      for (int t = 0; t < 8; t++) {
        int col = t * 16 + mrow;
        float o = (vals[t][r] - mean) * rs * gl[t] + bl[t];
        h[(size_t)rowi * H + col] = o;
        h_bf[(size_t)rowi * H + col] = bf16rne(o);
      }
    }
  }
}

// ---------------- K5: pooling, run-reduce over sorted batch ----------------
__global__ __launch_bounds__(256) void k_pool(
    const float* __restrict__ h, const int* __restrict__ batch,
    float* __restrict__ gsum, float* __restrict__ gcnt) {
  const int tid = threadIdx.x;
  const int col = tid & 127, half = tid >> 7;
  int n0 = blockIdx.x * 32 + half * 16;
  if (n0 >= NN) return;
  int end = n0 + 16; if (end > NN) end = NN;
  int cur = batch[n0];
  float run = h[(size_t)n0 * H + col];
  float cnt = 1.f;
  for (int n = n0 + 1; n < end; n++) {
    int b = batch[n];
    float v = h[(size_t)n * H + col];
    if (b == cur) { run += v; cnt += 1.f; }
    else {
      atomicAdd(&gsum[(size_t)cur * H + col], run);
      if (col == 0) atomicAdd(&gcnt[cur], cnt);
      cur = b; run = v; cnt = 1.f;
    }
  }
  atomicAdd(&gsum[(size_t)cur * H + col], run);
  if (col == 0) atomicAdd(&gcnt[cur], cnt);
}

// ---------------- K6: readout MLP ----------------
__global__ __launch_bounds__(128) void k_readout(
    const float* __restrict__ gsum, const float* __restrict__ gcnt,
    const float* __restrict__ W1, const float* __restrict__ b1,
    const float* __restrict__ W2, const float* __restrict__ b2,
    float* __restrict__ out) {
  __shared__ float gs[H];
  __shared__ float o1[H];
  int b = blockIdx.x, c = threadIdx.x;
  float cnt = fmaxf(gcnt[b], 1.f);
  gs[c] = gsum[b * H + c] / cnt;
  __syncthreads();
  float acc = b1[c];
  for (int k = 0; k < H; k++) acc = fmaf(gs[k], W1[k * H + c], acc);
  o1[c] = fmaxf(acc, 0.f);
  __syncthreads();
  if (c < 2) {
    float acc2 = b2[c];
    for (int k = 0; k < H; k++) acc2 = fmaf(o1[k], W2[k * 2 + c], acc2);
    out[b * 2 + c] = acc2;
  }
}

extern "C" void kernel_launch(void* const* d_in, const int* in_sizes, int n_in,
                              void* d_out, int out_size, void* d_ws, size_t ws_size,
                              hipStream_t stream) {
  (void)in_sizes; (void)n_in; (void)out_size; (void)ws_size;
  const float* x       = (const float*)d_in[0];
  const float* ea      = (const float*)d_in[1];
  const int*   eidx    = (const int*)d_in[2];
  const int*   batch   = (const int*)d_in[3];
  const float* n_enc_w = (const float*)d_in[4];
  const float* n_enc_b = (const float*)d_in[5];
  const float* e_enc_w = (const float*)d_in[6];
  const float* e_enc_b = (const float*)d_in[7];
  const float* n_ln_g  = (const float*)d_in[8];
  const float* n_ln_b  = (const float*)d_in[9];
  const float* e_ln_g  = (const float*)d_in[10];
  const float* e_ln_b  = (const float*)d_in[11];
  const float* msg_w1  = (const float*)d_in[12];
  const float* msg_b1  = (const float*)d_in[13];
  const float* msg_w2  = (const float*)d_in[14];
  const float* msg_b2  = (const float*)d_in[15];
  const float* gate_w  = (const float*)d_in[16];
  const float* gate_b  = (const float*)d_in[17];
  const float* res_w1  = (const float*)d_in[18];
  const float* res_b1  = (const float*)d_in[19];
  const float* res_w2  = (const float*)d_in[20];
  const float* res_b2  = (const float*)d_in[21];
  const float* ln_g    = (const float*)d_in[22];
  const float* ln_b    = (const float*)d_in[23];
  const float* ro_w1   = (const float*)d_in[24];
  const float* ro_b1   = (const float*)d_in[25];
  const float* ro_w2   = (const float*)d_in[26];
  const float* ro_b2   = (const float*)d_in[27];

  char* p = (char*)d_ws;
  float* h     = (float*)p;  p += (size_t)NN * H * 4;          // 25.6 MB
  short* h_bf  = (short*)p;  p += (size_t)NN * H * 2;          // 12.8 MB
  float* agg   = (float*)p;  p += (size_t)NN * H * 4;          // 25.6 MB
  short* ea_bf = (short*)p;  p += (size_t)NE * EIN * 2;        // 25.6 MB
  float* gsum  = (float*)p;  p += (size_t)NG * H * 4;
  float* gcnt  = (float*)p;  p += 1024;
  short* bgh   = (short*)p;  p += (size_t)3 * 65536 * 2;
  short* bm2   = (short*)p;  p += (size_t)3 * 16384 * 2;
  short* benc  = (short*)p;  p += (size_t)2048 * 2;
  short* brs1  = (short*)p;  p += (size_t)3 * 32768 * 2;
  short* brs2  = (short*)p;  p += (size_t)3 * 16384 * 2;
  unsigned* rowptr = (unsigned*)p; p += ((size_t)NN * 4 + 15) / 16 * 16;
  unsigned* cursor = (unsigned*)p; p += ((size_t)NN * 4 + 15) / 16 * 16;
  int* src_s   = (int*)p;    p += (size_t)NE * 4;
  int* dst_s   = (int*)p;    p += (size_t)NE * 4;
  // total ~97 MB

  const int node_blocks = (NN + 31) / 32;
  const int nup_blocks  = (NN + 63) / 64;   // 782
  const int edge_blocks = NE / 128;         // 6250, exact
  const int e256 = (NE + 255) / 256;
  const int conv_total = 3 * 65536 + 3 * 16384 + 2048 + 3 * 32768 + 3 * 16384;

  hipMemsetAsync(cursor, 0, (size_t)NN * 4, stream);
  k_count<<<e256, 256, 0, stream>>>(eidx, cursor);
  k_scan<<<1, 1024, 0, stream>>>(cursor, rowptr);
  hipMemsetAsync(cursor, 0, (size_t)NN * 4, stream);
  k_scatter<<<e256, 256, 0, stream>>>(eidx, ea, rowptr, cursor, src_s, dst_s, ea_bf);

  k_convert_w<<<(conv_total + 255) / 256, 256, 0, stream>>>(
      gate_w, msg_w1, msg_w2, e_enc_w, res_w1, res_w2,
      bgh, bm2, benc, brs1, brs2);
  k_node_encode<<<node_blocks, 256, 0, stream>>>(x, n_enc_w, n_enc_b, n_ln_g, n_ln_b, h, h_bf);

  // agg zeroed once here; k_node_up2 re-zeroes it for the next layer
  hipMemsetAsync(agg, 0, (size_t)NN * H * 4, stream);
  for (int l = 0; l < NL; l++) {
    k_edge_mfma<<<edge_blocks, 256, 0, stream>>>(
        ea_bf, src_s, dst_s, h_bf, benc, e_enc_b, e_ln_g, e_ln_b,
        bgh + (size_t)l * 65536, bm2 + (size_t)l * 16384,
        gate_b + l * H, msg_b1 + l * H, msg_b2 + l * H, agg);
    k_node_up2<<<nup_blocks, 256, 0, stream>>>(
        agg, h_bf, h,
        brs1 + (size_t)l * 32768, brs2 + (size_t)l * 16384,
        res_b1 + l * H, res_b2 + l * H,
        ln_g + l * H, ln_b + l * H, h, h_bf);
  }

  hipMemsetAsync(gsum, 0, ((size_t)NG * H + NG) * 4, stream);
  k_pool<<<(NN + 31) / 32, 256, 0, stream>>>(h, batch, gsum, gcnt);
  k_readout<<<NG, 128, 0, stream>>>(gsum, gcnt, ro_w1, ro_b1, ro_w2, ro_b2, (float*)d_out);
}